// Round 5
// baseline (2227.993 us; speedup 1.0000x reference)
//
#include <hip/hip_runtime.h>

// Problem constants (N=16384 nodes, D=32 state dim, H=128 hidden dim), fp32.
constexpr int GN = 16384;
constexpr int GD = 32;
constexpr int GH = 128;

// ---------------------------------------------------------------------------
// Kernel 1: messages = relu(states @ mW1 + mb1) @ mW2 + mb2       [N, D]
// Block: 256 threads, 16 rows per block. Grid: N/16 = 1024.
// ---------------------------------------------------------------------------
__global__ __launch_bounds__(256) void msg_mlp(
    const float* __restrict__ states, const float* __restrict__ mW1,
    const float* __restrict__ mb1, const float* __restrict__ mW2,
    const float* __restrict__ mb2, float* __restrict__ messages) {
  __shared__ float s_in[16][GD];    // 2 KB
  __shared__ float s_hid[16][GH];   // 8 KB
  const int t = threadIdx.x;
  const int row0 = blockIdx.x * 16;

  // stage 16 rows of states (contiguous, coalesced)
  for (int i = t; i < 16 * GD; i += 256)
    s_in[i >> 5][i & 31] = states[row0 * GD + i];
  __syncthreads();

  // phase 1: hidden[16][128]. thread -> h4 = (t&31)*4 (4 h-cols), rr = t>>5
  // handles rows rr and rr+8.
  {
    const int h4 = (t & 31) * 4;
    const int rr = t >> 5;  // 0..7
    float4 acc0 = {0.f, 0.f, 0.f, 0.f};
    float4 acc1 = {0.f, 0.f, 0.f, 0.f};
#pragma unroll
    for (int k = 0; k < GD; ++k) {
      const float4 w = *(const float4*)&mW1[k * GH + h4];
      const float c0 = s_in[rr][k];
      const float c1 = s_in[rr + 8][k];
      acc0.x = fmaf(c0, w.x, acc0.x); acc0.y = fmaf(c0, w.y, acc0.y);
      acc0.z = fmaf(c0, w.z, acc0.z); acc0.w = fmaf(c0, w.w, acc0.w);
      acc1.x = fmaf(c1, w.x, acc1.x); acc1.y = fmaf(c1, w.y, acc1.y);
      acc1.z = fmaf(c1, w.z, acc1.z); acc1.w = fmaf(c1, w.w, acc1.w);
    }
    const float4 b = *(const float4*)&mb1[h4];
    s_hid[rr][h4 + 0] = fmaxf(acc0.x + b.x, 0.f);
    s_hid[rr][h4 + 1] = fmaxf(acc0.y + b.y, 0.f);
    s_hid[rr][h4 + 2] = fmaxf(acc0.z + b.z, 0.f);
    s_hid[rr][h4 + 3] = fmaxf(acc0.w + b.w, 0.f);
    s_hid[rr + 8][h4 + 0] = fmaxf(acc1.x + b.x, 0.f);
    s_hid[rr + 8][h4 + 1] = fmaxf(acc1.y + b.y, 0.f);
    s_hid[rr + 8][h4 + 2] = fmaxf(acc1.z + b.z, 0.f);
    s_hid[rr + 8][h4 + 3] = fmaxf(acc1.w + b.w, 0.f);
  }
  __syncthreads();

  // phase 2: out[16][32]. thread -> d = t&31, slot = t>>5 handles rows slot, slot+8
  {
    const int d = t & 31;
    const int slot = t >> 5;  // 0..7
    float a0 = mb2[d], a1 = mb2[d];
#pragma unroll
    for (int k = 0; k < GH; ++k) {
      const float w = mW2[k * GD + d];
      a0 = fmaf(s_hid[slot][k], w, a0);
      a1 = fmaf(s_hid[slot + 8][k], w, a1);
    }
    messages[(row0 + slot) * GD + d] = a0;
    messages[(row0 + slot + 8) * GD + d] = a1;
  }
}

// ---------------------------------------------------------------------------
// Kernel 2: fused rowsum + aggregate:
//   agg[i,:] = (sum_j adj[i,j] * msg[j,:]) / max(sum_j adj[i,j], 1)
// Block: 256 threads = 4 waves, 32 rows per block. Each wave owns a j-quarter
// (4096 j). Lane tiling: dg = lane>>4 -> d in [dg*8, dg*8+8);
// rg = lane&15 -> rows rg*2, rg*2+1. 64 FMA per 10 float4 loads per lane-iter.
// Grid: N/32 = 512.
// ---------------------------------------------------------------------------
__global__ __launch_bounds__(256) void aggregate(
    const float* __restrict__ adj, const float* __restrict__ messages,
    float* __restrict__ aggregated) {
  const int i0 = blockIdx.x * 32;
  const int t = threadIdx.x;
  const int wave = t >> 6;        // 0..3 : j-quarter
  const int lane = t & 63;
  const int dg = lane >> 4;       // 0..3
  const int rg = lane & 15;       // 0..15
  const int r0 = rg * 2;
  const int r1 = rg * 2 + 1;
  const size_t jbase = (size_t)wave * (GN / 4);

  float acc0[8] = {0.f, 0.f, 0.f, 0.f, 0.f, 0.f, 0.f, 0.f};
  float acc1[8] = {0.f, 0.f, 0.f, 0.f, 0.f, 0.f, 0.f, 0.f};
  float rs0 = 0.f, rs1 = 0.f;

  const float* pa0 = adj + (size_t)(i0 + r0) * GN + jbase;
  const float* pa1 = adj + (size_t)(i0 + r1) * GN + jbase;
  const float* pm = messages + jbase * GD + dg * 8;

#pragma unroll 2
  for (int it = 0; it < GN / 4 / 4; ++it) {
    const float4 a0 = *(const float4*)pa0;
    const float4 a1 = *(const float4*)pa1;
    pa0 += 4; pa1 += 4;
    rs0 += (a0.x + a0.y) + (a0.z + a0.w);
    rs1 += (a1.x + a1.y) + (a1.z + a1.w);
#pragma unroll
    for (int jj = 0; jj < 4; ++jj) {
      const float4 m0 = *(const float4*)(pm + jj * GD);
      const float4 m1 = *(const float4*)(pm + jj * GD + 4);
      const float aj0 = (jj == 0) ? a0.x : (jj == 1) ? a0.y : (jj == 2) ? a0.z : a0.w;
      const float aj1 = (jj == 0) ? a1.x : (jj == 1) ? a1.y : (jj == 2) ? a1.z : a1.w;
      acc0[0] = fmaf(aj0, m0.x, acc0[0]); acc0[1] = fmaf(aj0, m0.y, acc0[1]);
      acc0[2] = fmaf(aj0, m0.z, acc0[2]); acc0[3] = fmaf(aj0, m0.w, acc0[3]);
      acc0[4] = fmaf(aj0, m1.x, acc0[4]); acc0[5] = fmaf(aj0, m1.y, acc0[5]);
      acc0[6] = fmaf(aj0, m1.z, acc0[6]); acc0[7] = fmaf(aj0, m1.w, acc0[7]);
      acc1[0] = fmaf(aj1, m0.x, acc1[0]); acc1[1] = fmaf(aj1, m0.y, acc1[1]);
      acc1[2] = fmaf(aj1, m0.z, acc1[2]); acc1[3] = fmaf(aj1, m0.w, acc1[3]);
      acc1[4] = fmaf(aj1, m1.x, acc1[4]); acc1[5] = fmaf(aj1, m1.y, acc1[5]);
      acc1[6] = fmaf(aj1, m1.z, acc1[6]); acc1[7] = fmaf(aj1, m1.w, acc1[7]);
    }
    pm += 4 * GD;
  }

  // cross-wave (j-quarter) reduction + degree normalize
  __shared__ float red[4][32][32];   // 16 KB : [wave][row][d]
  __shared__ float rsred[4][32];     // 512 B
#pragma unroll
  for (int q = 0; q < 8; ++q) {
    red[wave][r0][dg * 8 + q] = acc0[q];
    red[wave][r1][dg * 8 + q] = acc1[q];
  }
  if (dg == 0) {
    rsred[wave][r0] = rs0;
    rsred[wave][r1] = rs1;
  }
  __syncthreads();

  for (int o = t; o < 32 * 32; o += 256) {
    const int r = o >> 5;
    const int d = o & 31;
    const float s = (red[0][r][d] + red[1][r][d]) + (red[2][r][d] + red[3][r][d]);
    float deg = (rsred[0][r] + rsred[1][r]) + (rsred[2][r] + rsred[3][r]);
    deg = fmaxf(deg, 1.0f);
    aggregated[(size_t)(i0 + r) * GD + d] = s / deg;
  }
}

// ---------------------------------------------------------------------------
// Kernel 3: updates = relu([states, agg] @ uW1 + ub1) @ uW2 + ub2   [N, D]
// Same structure as kernel 1, combined dim = 64. Grid: N/16 = 1024.
// ---------------------------------------------------------------------------
__global__ __launch_bounds__(256) void upd_mlp(
    const float* __restrict__ states, const float* __restrict__ aggregated,
    const float* __restrict__ uW1, const float* __restrict__ ub1,
    const float* __restrict__ uW2, const float* __restrict__ ub2,
    float* __restrict__ out) {
  __shared__ float s_in[16][2 * GD];  // 4 KB
  __shared__ float s_hid[16][GH];     // 8 KB
  const int t = threadIdx.x;
  const int row0 = blockIdx.x * 16;

  for (int i = t; i < 16 * GD; i += 256) {
    const int r = i >> 5;
    const int c = i & 31;
    s_in[r][c] = states[(row0 + r) * GD + c];
    s_in[r][GD + c] = aggregated[(row0 + r) * GD + c];
  }
  __syncthreads();

  // phase 1: hidden[16][128] over K=64
  {
    const int h4 = (t & 31) * 4;
    const int rr = t >> 5;  // 0..7
    float4 acc0 = {0.f, 0.f, 0.f, 0.f};
    float4 acc1 = {0.f, 0.f, 0.f, 0.f};
#pragma unroll
    for (int k = 0; k < 2 * GD; ++k) {
      const float4 w = *(const float4*)&uW1[k * GH + h4];
      const float c0 = s_in[rr][k];
      const float c1 = s_in[rr + 8][k];
      acc0.x = fmaf(c0, w.x, acc0.x); acc0.y = fmaf(c0, w.y, acc0.y);
      acc0.z = fmaf(c0, w.z, acc0.z); acc0.w = fmaf(c0, w.w, acc0.w);
      acc1.x = fmaf(c1, w.x, acc1.x); acc1.y = fmaf(c1, w.y, acc1.y);
      acc1.z = fmaf(c1, w.z, acc1.z); acc1.w = fmaf(c1, w.w, acc1.w);
    }
    const float4 b = *(const float4*)&ub1[h4];
    s_hid[rr][h4 + 0] = fmaxf(acc0.x + b.x, 0.f);
    s_hid[rr][h4 + 1] = fmaxf(acc0.y + b.y, 0.f);
    s_hid[rr][h4 + 2] = fmaxf(acc0.z + b.z, 0.f);
    s_hid[rr][h4 + 3] = fmaxf(acc0.w + b.w, 0.f);
    s_hid[rr + 8][h4 + 0] = fmaxf(acc1.x + b.x, 0.f);
    s_hid[rr + 8][h4 + 1] = fmaxf(acc1.y + b.y, 0.f);
    s_hid[rr + 8][h4 + 2] = fmaxf(acc1.z + b.z, 0.f);
    s_hid[rr + 8][h4 + 3] = fmaxf(acc1.w + b.w, 0.f);
  }
  __syncthreads();

  // phase 2: out[16][32] over K=128
  {
    const int d = t & 31;
    const int slot = t >> 5;  // 0..7
    float a0 = ub2[d], a1 = ub2[d];
#pragma unroll
    for (int k = 0; k < GH; ++k) {
      const float w = uW2[k * GD + d];
      a0 = fmaf(s_hid[slot][k], w, a0);
      a1 = fmaf(s_hid[slot + 8][k], w, a1);
    }
    out[(row0 + slot) * GD + d] = a0;
    out[(row0 + slot + 8) * GD + d] = a1;
  }
}

extern "C" void kernel_launch(void* const* d_in, const int* in_sizes, int n_in,
                              void* d_out, int out_size, void* d_ws, size_t ws_size,
                              hipStream_t stream) {
  const float* states = (const float*)d_in[0];
  const float* adj    = (const float*)d_in[1];
  const float* mW1    = (const float*)d_in[2];
  const float* mb1    = (const float*)d_in[3];
  const float* mW2    = (const float*)d_in[4];
  const float* mb2    = (const float*)d_in[5];
  const float* uW1    = (const float*)d_in[6];
  const float* ub1    = (const float*)d_in[7];
  const float* uW2    = (const float*)d_in[8];
  const float* ub2    = (const float*)d_in[9];
  float* out = (float*)d_out;

  float* messages   = (float*)d_ws;              // N*D floats = 2 MB
  float* aggregated = messages + (size_t)GN * GD; // N*D floats = 2 MB

  msg_mlp<<<dim3(GN / 16), dim3(256), 0, stream>>>(states, mW1, mb1, mW2, mb2,
                                                   messages);
  aggregate<<<dim3(GN / 32), dim3(256), 0, stream>>>(adj, messages, aggregated);
  upd_mlp<<<dim3(GN / 16), dim3(256), 0, stream>>>(states, aggregated, uW1, ub1,
                                                   uW2, ub2, out);
}